// Round 10
// baseline (296.686 us; speedup 1.0000x reference)
//
#include <hip/hip_runtime.h>
#include <math.h>
#include <float.h>

// DeepSeek V3 router, round 10.
// R9 validated: 32x32x16 split-fp16 single-acc GEMM, A via swizzled LDS,
// B global->reg from fragment-packed L2-resident planes, conflicts = 0.
// R10: fill the machine. splitK=8 -> grid 1024 (3 blocks/CU resident at
// 156 unified regs, launch_bounds(256,3)); ks = XCD id so each XCD's L2
// holds exactly its 0.92MB B slice; A-prefetch deepened to 2 phases via
// triple-buffered sA + two named va register sets.
// Numerics (validated R7-R9): acc += a0*b0; acc += (a1*2^-6)*(b0*2^-5);
// acc += (a0*2^-5)*b3;  a0=fp16(x), a1=fp16(res_x*2048), b0=fp16(256w),
// b3=fp16(res_w256*32); logit = acc/256.

#define TDIM 8192
#define DDIM 7168
#define EDIM 256
#define KT   (DDIM / 32)   // 224 k-tiles of 32

typedef _Float16 h8 __attribute__((ext_vector_type(8)));
typedef float f16v __attribute__((ext_vector_type(16)));

// ---------------- K1: W -> 32x32x16-fragment-packed fp16 planes ------------
// Fragment lane l <-> (e = l&31, k = kf*16 + (l>>5)*8 + j).
// Offset(halfs) = (((p*8 + cf)*KT + kt)*2 + kf)*512 + lane*8,
//   cf = e>>5, kt = k>>5, kf = (k>>4)&1, lane = (e&31) + 32*((k>>3)&1).
__global__ __launch_bounds__(256)
void convert_w(const float* __restrict__ W, _Float16* __restrict__ Bp)
{
    __shared__ _Float16 l0[64][80];
    __shared__ _Float16 l1[64][80];
    const int t = threadIdx.x;
    const int kt = blockIdx.x * 64;
    const int et = blockIdx.y * 64;
#pragma unroll
    for (int i = 0; i < 16; ++i) {
        const int kr = (t >> 6) * 16 + i;
        const int ec = t & 63;
        const float w = W[(size_t)(kt + kr) * EDIM + et + ec] * 256.f;
        const _Float16 h0 = (_Float16)w;
        const _Float16 h1 = (_Float16)((w - (float)h0) * 32.f);
        l0[ec][kr] = h0;
        l1[ec][kr] = h1;
    }
    __syncthreads();
#pragma unroll
    for (int j = 0; j < 2; ++j) {
        const int er = t >> 2;
        const int kc = ((t & 3) + 4 * j) * 8;
        const int e  = et + er;
        const int k  = kt + kc;
        const int cf   = e >> 5;
        const int lane = (e & 31) + 32 * ((k >> 3) & 1);
        const int kf   = (k >> 4) & 1;
        const int ktl  = k >> 5;
        const uint4 v0 = *(const uint4*)&l0[er][kc];
        const uint4 v1 = *(const uint4*)&l1[er][kc];
        const size_t o0 = (((size_t)(0 * 8 + cf) * KT + ktl) * 2 + kf) * 512 + lane * 8;
        const size_t o1 = (((size_t)(1 * 8 + cf) * KT + ktl) * 2 + kf) * 512 + lane * 8;
        *(uint4*)&Bp[o0] = v0;
        *(uint4*)&Bp[o1] = v1;
    }
}

// ---------------- K2: 32x32x16 split-fp16 GEMM, A in LDS / B from L2 -------
__global__ __launch_bounds__(256, 3)
void gemm_mfma(const float* __restrict__ X,
               const _Float16* __restrict__ Bp,
               float* __restrict__ P,
               int splitK, int kLen)
{
    __shared__ _Float16 sA[3][2][64][32];   // 24 KB: 3-deep A pipeline

    const int t    = threadIdx.x;
    const int lane = t & 63;
    const int w    = t >> 6;                // wave 0..3 -> cols w*64..+63

    // ks = xcd (splitK=8): each XCD's L2 caches exactly its B slice.
    const int xcd = blockIdx.x & 7;
    const int jb  = blockIdx.x >> 3;
    const int ks  = xcd % splitK;
    const int mb  = jb * (8 / splitK) + xcd / splitK;
    const int m0  = mb * 64;
    const int kbeg = ks * kLen;
    const int nt   = kLen >> 5;
    const int ktg0 = kbeg >> 5;

    f16v acc[2][2];
#pragma unroll
    for (int h = 0; h < 2; ++h)
#pragma unroll
        for (int n = 0; n < 2; ++n) acc[h][n] = (f16v)0.f;

    // A staging: thread -> row t>>2 (0..63), granule g=t&3 (8 floats)
    const int rowA  = t >> 2;
    const int gA    = t & 3;
    const float* xg = X + (size_t)(m0 + rowA) * DDIM + kbeg + gA * 8;
    const int slotA = (gA ^ ((rowA >> 2) & 3)) * 8;   // halfs

    const _Float16* bbase = Bp + lane * 8;

    float4 vaA0, vaA1, vaB0, vaB1;

#define LOADA(R0, R1, kb)                                                     \
    {                                                                         \
        R0 = *(const float4*)(xg + (kb));                                     \
        R1 = *(const float4*)(xg + (kb) + 4);                                 \
    }

#define WRITEA(buf, R0, R1)                                                   \
    {                                                                         \
        h8 p0, p1;                                                            \
        const float xv[8] = {R0.x, R0.y, R0.z, R0.w,                          \
                             R1.x, R1.y, R1.z, R1.w};                         \
        _Pragma("unroll")                                                     \
        for (int q = 0; q < 8; ++q) {                                         \
            const _Float16 h0 = (_Float16)xv[q];                              \
            p0[q] = h0;                                                       \
            p1[q] = (_Float16)((xv[q] - (float)h0) * 2048.f);                 \
        }                                                                     \
        *(h8*)&sA[buf][0][rowA][slotA] = p0;                                  \
        *(h8*)&sA[buf][1][rowA][slotA] = p1;                                  \
    }

#define BLOAD(RB, TI)                                                         \
    {                                                                         \
        _Pragma("unroll")                                                     \
        for (int p = 0; p < 2; ++p)                                           \
        _Pragma("unroll")                                                     \
        for (int n = 0; n < 2; ++n)                                           \
        _Pragma("unroll")                                                     \
        for (int kf = 0; kf < 2; ++kf)                                        \
            RB[p][n][kf] = *(const h8*)(bbase +                               \
                (((size_t)(p * 8 + w * 2 + n) * KT + ktg0 + (TI)) * 2 + kf) * 512); \
    }

#define AREAD(CUR)                                                            \
    {                                                                         \
        _Pragma("unroll")                                                     \
        for (int h = 0; h < 2; ++h)                                           \
        _Pragma("unroll")                                                     \
        for (int kf = 0; kf < 2; ++kf) {                                      \
            const int rr = h * 32 + (lane & 31);                              \
            const int sl = (((lane >> 5) + 2 * kf) ^ ((rr >> 2) & 3)) * 8;    \
            a0[h][kf] = *(const h8*)&sA[CUR][0][rr][sl];                      \
            a1[h][kf] = *(const h8*)&sA[CUR][1][rr][sl];                      \
        }                                                                     \
    }

#define MFMA3(RB)                                                             \
    {                                                                         \
        __builtin_amdgcn_s_setprio(1);                                        \
        _Pragma("unroll")                                                     \
        for (int h = 0; h < 2; ++h)                                           \
        _Pragma("unroll")                                                     \
        for (int n = 0; n < 2; ++n)                                           \
        _Pragma("unroll")                                                     \
        for (int kf = 0; kf < 2; ++kf)                                        \
            acc[h][n] = __builtin_amdgcn_mfma_f32_32x32x16_f16(               \
                a0[h][kf], RB[0][n][kf], acc[h][n], 0, 0, 0);                 \
        _Pragma("unroll")                                                     \
        for (int n = 0; n < 2; ++n)                                           \
        _Pragma("unroll")                                                     \
        for (int kf = 0; kf < 2; ++kf)                                        \
        _Pragma("unroll")                                                     \
        for (int q = 0; q < 8; ++q) RB[0][n][kf][q] *= S5;                    \
        _Pragma("unroll")                                                     \
        for (int h = 0; h < 2; ++h)                                           \
        _Pragma("unroll")                                                     \
        for (int kf = 0; kf < 2; ++kf)                                        \
        _Pragma("unroll")                                                     \
        for (int q = 0; q < 8; ++q) a1[h][kf][q] *= S6;                       \
        _Pragma("unroll")                                                     \
        for (int h = 0; h < 2; ++h)                                           \
        _Pragma("unroll")                                                     \
        for (int n = 0; n < 2; ++n)                                           \
        _Pragma("unroll")                                                     \
        for (int kf = 0; kf < 2; ++kf)                                        \
            acc[h][n] = __builtin_amdgcn_mfma_f32_32x32x16_f16(               \
                a1[h][kf], RB[0][n][kf], acc[h][n], 0, 0, 0);                 \
        _Pragma("unroll")                                                     \
        for (int h = 0; h < 2; ++h)                                           \
        _Pragma("unroll")                                                     \
        for (int kf = 0; kf < 2; ++kf)                                        \
        _Pragma("unroll")                                                     \
        for (int q = 0; q < 8; ++q) a0[h][kf][q] *= S5;                       \
        _Pragma("unroll")                                                     \
        for (int h = 0; h < 2; ++h)                                           \
        _Pragma("unroll")                                                     \
        for (int n = 0; n < 2; ++n)                                           \
        _Pragma("unroll")                                                     \
        for (int kf = 0; kf < 2; ++kf)                                        \
            acc[h][n] = __builtin_amdgcn_mfma_f32_32x32x16_f16(               \
                a0[h][kf], RB[1][n][kf], acc[h][n], 0, 0, 0);                 \
        __builtin_amdgcn_s_setprio(0);                                        \
    }

    const _Float16 S5 = (_Float16)0.03125f;     // 2^-5
    const _Float16 S6 = (_Float16)0.015625f;    // 2^-6

    h8 bE[2][2][2], bO[2][2][2];

    // ---- prologue: sA[0]=t0, sA[1]=t1; vaA holds t2 in flight; bE=B(0) ----
    LOADA(vaA0, vaA1, 0);
    LOADA(vaB0, vaB1, 32);
    BLOAD(bE, 0);
    WRITEA(0, vaA0, vaA1);
    WRITEA(1, vaB0, vaB1);
    if (nt > 2) LOADA(vaA0, vaA1, 2 * 32);
    asm volatile("s_waitcnt lgkmcnt(0)" ::: "memory");
    __builtin_amdgcn_s_barrier();

    int cur = 0;                     // sA buffer holding current tile
    for (int ti = 0; ti < nt; ti += 2) {
        {   // even phase: tile ti (sA[cur], bE); vaA holds ti+2
            h8 a0[2][2], a1[2][2];
            const int wr = (cur >= 1) ? cur - 1 : cur + 2;   // (cur+2)%3
            if (ti + 1 < nt) BLOAD(bO, ti + 1);
            if (ti + 3 < nt) LOADA(vaB0, vaB1, (ti + 3) * 32);
            AREAD(cur);
            MFMA3(bE);
            if (ti + 2 < nt) WRITEA(wr, vaA0, vaA1);
            asm volatile("s_waitcnt lgkmcnt(0)" ::: "memory");
            __builtin_amdgcn_s_barrier();
            cur = (cur < 2) ? cur + 1 : 0;
        }
        if (ti + 1 < nt) {   // odd phase: tile ti+1 (sA[cur], bO); vaB holds ti+3
            h8 a0[2][2], a1[2][2];
            const int wr = (cur >= 1) ? cur - 1 : cur + 2;
            if (ti + 2 < nt) BLOAD(bE, ti + 2);
            if (ti + 4 < nt) LOADA(vaA0, vaA1, (ti + 4) * 32);
            AREAD(cur);
            MFMA3(bO);
            if (ti + 3 < nt) WRITEA(wr, vaB0, vaB1);
            asm volatile("s_waitcnt lgkmcnt(0)" ::: "memory");
            __builtin_amdgcn_s_barrier();
            cur = (cur < 2) ? cur + 1 : 0;
        }
    }

    // epilogue: logit = acc/256; C/D: col=lane&31, row=(r&3)+8*(r>>2)+4*(lane>>5)
    const float s0 = 1.f / 256.f;
#pragma unroll
    for (int h = 0; h < 2; ++h)
#pragma unroll
        for (int n = 0; n < 2; ++n)
#pragma unroll
            for (int r = 0; r < 16; ++r) {
                const int row = (r & 3) + 8 * (r >> 2) + 4 * (lane >> 5);
                const int gr  = m0 + h * 32 + row;
                const int gc  = w * 64 + n * 32 + (lane & 31);
                P[((size_t)ks * TDIM + gr) * EDIM + gc] = acc[h][n][r] * s0;
            }
}

// ---------------- K3: reduce + sigmoid + grouped top-k route ----------------
__global__ __launch_bounds__(256, 4)
void route_kernel(const float* __restrict__ P,
                  const float* __restrict__ B,
                  float* __restrict__ out,
                  int splitK)
{
    const int t    = threadIdx.x;
    const int lane = t & 63;
    const int wid  = t >> 6;
    const int tok0 = blockIdx.x * 32 + wid * 8;

    const float4 bv4 = *(const float4*)&B[lane * 4];
    const float bb[4] = {bv4.x, bv4.y, bv4.z, bv4.w};
    const int g = lane >> 3;

#pragma unroll
    for (int i = 0; i < 8; ++i) {
        const int tok = tok0 + i;
        float a[4] = {0.f, 0.f, 0.f, 0.f};
        for (int ksl = 0; ksl < splitK; ++ksl) {
            const float4 pv =
                *(const float4*)&P[((size_t)ksl * TDIM + tok) * EDIM + lane * 4];
            a[0] += pv.x; a[1] += pv.y; a[2] += pv.z; a[3] += pv.w;
        }
        float v[4], s[4];
#pragma unroll
        for (int jq = 0; jq < 4; ++jq) {
            v[jq] = 1.f / (1.f + expf(-a[jq]));
            s[jq] = v[jq] + bb[jq];
        }
        float t1 = s[0], t2 = -FLT_MAX;
#pragma unroll
        for (int jq = 1; jq < 4; ++jq) {
            if (s[jq] > t1) { t2 = t1; t1 = s[jq]; }
            else if (s[jq] > t2) t2 = s[jq];
        }
#pragma unroll
        for (int d = 1; d < 8; d <<= 1) {
            float o1 = __shfl_xor(t1, d);
            float o2 = __shfl_xor(t2, d);
            float n1 = fmaxf(t1, o1);
            float n2 = fmaxf(fminf(t1, o1), fmaxf(t2, o2));
            t1 = n1; t2 = n2;
        }
        const float gsc = t1 + t2;
        float gs[8];
#pragma unroll
        for (int q = 0; q < 8; ++q) gs[q] = __shfl(gsc, q * 8);
        int gmask = 0;
#pragma unroll
        for (int it = 0; it < 4; ++it) {
            float bvv = -FLT_MAX; int bg = 0;
#pragma unroll
            for (int q = 0; q < 8; ++q) {
                const bool avail = ((gmask >> q) & 1) == 0;
                if (avail && gs[q] > bvv) { bvv = gs[q]; bg = q; }
            }
            gmask |= (1 << bg);
        }
        if (((gmask >> g) & 1) == 0) { s[0] = 0.f; s[1] = 0.f; s[2] = 0.f; s[3] = 0.f; }

        float wk[8]; int ik[8]; float wsum = 0.f;
#pragma unroll
        for (int it = 0; it < 8; ++it) {
            float bvv = s[0]; int bi = lane * 4; float bs = v[0];
#pragma unroll
            for (int jq = 1; jq < 4; ++jq)
                if (s[jq] > bvv) { bvv = s[jq]; bi = lane * 4 + jq; bs = v[jq]; }
#pragma unroll
            for (int d = 1; d < 64; d <<= 1) {
                float ov = __shfl_xor(bvv, d);
                int   oi = __shfl_xor(bi, d);
                float os = __shfl_xor(bs, d);
                if (ov > bvv || (ov == bvv && oi < bi)) { bvv = ov; bi = oi; bs = os; }
            }
            wk[it] = bs; ik[it] = bi; wsum += bs;
#pragma unroll
            for (int jq = 0; jq < 4; ++jq)
                if (bi == lane * 4 + jq) s[jq] = -FLT_MAX;
        }
        const float den = wsum + 1e-20f;
        if (lane == 0) {
#pragma unroll
            for (int q = 0; q < 8; ++q) {
                out[(size_t)tok * 8 + q] = wk[q] / den * 2.5f;
                out[(size_t)TDIM * 8 + (size_t)tok * 8 + q] = (float)ik[q];
            }
        }
    }
}

extern "C" void kernel_launch(void* const* d_in, const int* in_sizes, int n_in,
                              void* d_out, int out_size, void* d_ws, size_t ws_size,
                              hipStream_t stream)
{
    (void)in_sizes; (void)n_in; (void)out_size;
    const float* x    = (const float*)d_in[0];
    const float* kern = (const float*)d_in[1];
    const float* bias = (const float*)d_in[2];
    float* out = (float*)d_out;

    const size_t packedBytes = (size_t)2 * 8 * KT * 2 * 512 * 2;   // 7.34 MB
    int splitK = 8;
    while (splitK > 1 &&
           (size_t)splitK * TDIM * EDIM * 4 + packedBytes > ws_size)
        splitK >>= 1;

    float* P = (float*)d_ws;
    _Float16* Bp = (_Float16*)((char*)d_ws + (size_t)splitK * TDIM * EDIM * 4);

    convert_w<<<dim3(DDIM / 64, EDIM / 64), 256, 0, stream>>>(kern, Bp);
    gemm_mfma<<<(TDIM / 64) * splitK, 256, 0, stream>>>(
        x, Bp, P, splitK, DDIM / splitK);
    route_kernel<<<TDIM / 32, 256, 0, stream>>>(P, bias, out, splitK);
}

// Round 11
// 165.663 us; speedup vs baseline: 1.7909x; 1.7909x over previous
//
#include <hip/hip_runtime.h>
#include <math.h>
#include <float.h>

// DeepSeek V3 router, round 11.
// R9 base (validated: 32x32x16 split-fp16 single-acc, A via swizzled LDS,
// B global->reg fragment-packed L2-resident, conflicts 0, splitK=4 grid 512)
// + deeper pipeline WITHOUT R10's regressions:
//  - triple-buffer sA + two named va sets: X HBM latency (~900cy) covered by
//    ~1 full phase (R9 consumed va in the same phase it was loaded).
//  - A-fragment reg prefetch one phase ahead (aE/aO named sets, even/odd
//    unrolled): ds_read latency hides under the previous MFMA cluster.
//  - B regs (bE/bO) one phase ahead as before (L2 hit ~200cy, covered).
// Numerics (validated R7-R10): acc += a0*b0; acc += (a1*2^-6)*(b0*2^-5);
// acc += (a0*2^-5)*b3; a0=fp16(x), a1=fp16(res_x*2048), b0=fp16(256w),
// b3=fp16(res_w256*32); logit = acc/256.

#define TDIM 8192
#define DDIM 7168
#define EDIM 256
#define KT   (DDIM / 32)   // 224 k-tiles of 32

typedef _Float16 h8 __attribute__((ext_vector_type(8)));
typedef float f16v __attribute__((ext_vector_type(16)));

// ---------------- K1: W -> 32x32x16-fragment-packed fp16 planes ------------
__global__ __launch_bounds__(256)
void convert_w(const float* __restrict__ W, _Float16* __restrict__ Bp)
{
    __shared__ _Float16 l0[64][80];
    __shared__ _Float16 l1[64][80];
    const int t = threadIdx.x;
    const int kt = blockIdx.x * 64;
    const int et = blockIdx.y * 64;
#pragma unroll
    for (int i = 0; i < 16; ++i) {
        const int kr = (t >> 6) * 16 + i;
        const int ec = t & 63;
        const float w = W[(size_t)(kt + kr) * EDIM + et + ec] * 256.f;
        const _Float16 h0 = (_Float16)w;
        const _Float16 h1 = (_Float16)((w - (float)h0) * 32.f);
        l0[ec][kr] = h0;
        l1[ec][kr] = h1;
    }
    __syncthreads();
#pragma unroll
    for (int j = 0; j < 2; ++j) {
        const int er = t >> 2;
        const int kc = ((t & 3) + 4 * j) * 8;
        const int e  = et + er;
        const int k  = kt + kc;
        const int cf   = e >> 5;
        const int lane = (e & 31) + 32 * ((k >> 3) & 1);
        const int kf   = (k >> 4) & 1;
        const int ktl  = k >> 5;
        const uint4 v0 = *(const uint4*)&l0[er][kc];
        const uint4 v1 = *(const uint4*)&l1[er][kc];
        const size_t o0 = (((size_t)(0 * 8 + cf) * KT + ktl) * 2 + kf) * 512 + lane * 8;
        const size_t o1 = (((size_t)(1 * 8 + cf) * KT + ktl) * 2 + kf) * 512 + lane * 8;
        *(uint4*)&Bp[o0] = v0;
        *(uint4*)&Bp[o1] = v1;
    }
}

// ---------------- K2: 32x32x16 split-fp16 GEMM, A in LDS / B from L2 -------
__global__ __launch_bounds__(256, 2)
void gemm_mfma(const float* __restrict__ X,
               const _Float16* __restrict__ Bp,
               float* __restrict__ P,
               int splitK, int kLen)
{
    __shared__ _Float16 sA[3][2][64][32];   // 24 KB, 3-deep A pipeline

    const int t    = threadIdx.x;
    const int lane = t & 63;
    const int w    = t >> 6;                // wave 0..3 -> cols w*64..+63

    const int xcd = blockIdx.x & 7;
    const int jb  = blockIdx.x >> 3;
    const int ks  = xcd % splitK;
    const int mb  = jb * (8 / splitK) + xcd / splitK;
    const int m0  = mb * 64;
    const int kbeg = ks * kLen;
    const int nt   = kLen >> 5;
    const int ktg0 = kbeg >> 5;

    f16v acc[2][2];
#pragma unroll
    for (int h = 0; h < 2; ++h)
#pragma unroll
        for (int n = 0; n < 2; ++n) acc[h][n] = (f16v)0.f;

    const int rowA  = t >> 2;
    const int gA    = t & 3;
    const float* xg = X + (size_t)(m0 + rowA) * DDIM + kbeg + gA * 8;
    const int slotA = (gA ^ ((rowA >> 2) & 3)) * 8;

    const _Float16* bbase = Bp + lane * 8;

    float4 vaA0, vaA1, vaB0, vaB1;

#define LOADA(R0, R1, kb)                                                     \
    {                                                                         \
        R0 = *(const float4*)(xg + (kb));                                     \
        R1 = *(const float4*)(xg + (kb) + 4);                                 \
    }

#define WRITEA(buf, R0, R1)                                                   \
    {                                                                         \
        h8 p0, p1;                                                            \
        const float xv[8] = {R0.x, R0.y, R0.z, R0.w,                          \
                             R1.x, R1.y, R1.z, R1.w};                         \
        _Pragma("unroll")                                                     \
        for (int q = 0; q < 8; ++q) {                                         \
            const _Float16 h0 = (_Float16)xv[q];                              \
            p0[q] = h0;                                                       \
            p1[q] = (_Float16)((xv[q] - (float)h0) * 2048.f);                 \
        }                                                                     \
        *(h8*)&sA[buf][0][rowA][slotA] = p0;                                  \
        *(h8*)&sA[buf][1][rowA][slotA] = p1;                                  \
    }

#define BLOAD(RB, TI)                                                         \
    {                                                                         \
        _Pragma("unroll")                                                     \
        for (int p = 0; p < 2; ++p)                                           \
        _Pragma("unroll")                                                     \
        for (int n = 0; n < 2; ++n)                                           \
        _Pragma("unroll")                                                     \
        for (int kf = 0; kf < 2; ++kf)                                        \
            RB[p][n][kf] = *(const h8*)(bbase +                               \
                (((size_t)(p * 8 + w * 2 + n) * KT + ktg0 + (TI)) * 2 + kf) * 512); \
    }

#define AREAD(A0, A1, CUR)                                                    \
    {                                                                         \
        _Pragma("unroll")                                                     \
        for (int h = 0; h < 2; ++h)                                           \
        _Pragma("unroll")                                                     \
        for (int kf = 0; kf < 2; ++kf) {                                      \
            const int rr = h * 32 + (lane & 31);                              \
            const int sl = (((lane >> 5) + 2 * kf) ^ ((rr >> 2) & 3)) * 8;    \
            A0[h][kf] = *(const h8*)&sA[CUR][0][rr][sl];                      \
            A1[h][kf] = *(const h8*)&sA[CUR][1][rr][sl];                      \
        }                                                                     \
    }

#define MFMA3(A0, A1, RB)                                                     \
    {                                                                         \
        __builtin_amdgcn_s_setprio(1);                                        \
        _Pragma("unroll")                                                     \
        for (int h = 0; h < 2; ++h)                                           \
        _Pragma("unroll")                                                     \
        for (int n = 0; n < 2; ++n)                                           \
        _Pragma("unroll")                                                     \
        for (int kf = 0; kf < 2; ++kf)                                        \
            acc[h][n] = __builtin_amdgcn_mfma_f32_32x32x16_f16(               \
                A0[h][kf], RB[0][n][kf], acc[h][n], 0, 0, 0);                 \
        _Pragma("unroll")                                                     \
        for (int n = 0; n < 2; ++n)                                           \
        _Pragma("unroll")                                                     \
        for (int kf = 0; kf < 2; ++kf)                                        \
        _Pragma("unroll")                                                     \
        for (int q = 0; q < 8; ++q) RB[0][n][kf][q] *= S5;                    \
        _Pragma("unroll")                                                     \
        for (int h = 0; h < 2; ++h)                                           \
        _Pragma("unroll")                                                     \
        for (int kf = 0; kf < 2; ++kf)                                        \
        _Pragma("unroll")                                                     \
        for (int q = 0; q < 8; ++q) A1[h][kf][q] *= S6;                       \
        _Pragma("unroll")                                                     \
        for (int h = 0; h < 2; ++h)                                           \
        _Pragma("unroll")                                                     \
        for (int n = 0; n < 2; ++n)                                           \
        _Pragma("unroll")                                                     \
        for (int kf = 0; kf < 2; ++kf)                                        \
            acc[h][n] = __builtin_amdgcn_mfma_f32_32x32x16_f16(               \
                A1[h][kf], RB[0][n][kf], acc[h][n], 0, 0, 0);                 \
        _Pragma("unroll")                                                     \
        for (int h = 0; h < 2; ++h)                                           \
        _Pragma("unroll")                                                     \
        for (int kf = 0; kf < 2; ++kf)                                        \
        _Pragma("unroll")                                                     \
        for (int q = 0; q < 8; ++q) A0[h][kf][q] *= S5;                       \
        _Pragma("unroll")                                                     \
        for (int h = 0; h < 2; ++h)                                           \
        _Pragma("unroll")                                                     \
        for (int n = 0; n < 2; ++n)                                           \
        _Pragma("unroll")                                                     \
        for (int kf = 0; kf < 2; ++kf)                                        \
            acc[h][n] = __builtin_amdgcn_mfma_f32_32x32x16_f16(               \
                A0[h][kf], RB[1][n][kf], acc[h][n], 0, 0, 0);                 \
        __builtin_amdgcn_s_setprio(0);                                        \
    }

    const _Float16 S5 = (_Float16)0.03125f;     // 2^-5
    const _Float16 S6 = (_Float16)0.015625f;    // 2^-6

    h8 aE0[2][2], aE1[2][2], aO0[2][2], aO1[2][2];
    h8 bE[2][2][2], bO[2][2][2];

    // ---- prologue: buf0=t0, buf1=t1; vaA=t2 in flight; bE=B(0) ----
    LOADA(vaA0, vaA1, 0);
    LOADA(vaB0, vaB1, 32);
    BLOAD(bE, 0);
    WRITEA(0, vaA0, vaA1);
    WRITEA(1, vaB0, vaB1);
    if (nt > 2) LOADA(vaA0, vaA1, 64);
    asm volatile("s_waitcnt lgkmcnt(0)" ::: "memory");
    __builtin_amdgcn_s_barrier();
    AREAD(aE0, aE1, 0);          // frags for t0

    int cur = 0;
    for (int ti = 0; ti < nt; ti += 2) {
        const int nxt = (cur < 2) ? cur + 1 : 0;
        const int wr  = (nxt < 2) ? nxt + 1 : 0;
        // ---- even phase: tile ti (regs aE, bE from sA[cur]) ----
        if (ti + 1 < nt) { BLOAD(bO, ti + 1); AREAD(aO0, aO1, nxt); }
        if (ti + 3 < nt) LOADA(vaB0, vaB1, (ti + 3) * 32);
        MFMA3(aE0, aE1, bE);
        if (ti + 2 < nt) WRITEA(wr, vaA0, vaA1);
        asm volatile("s_waitcnt lgkmcnt(0)" ::: "memory");
        __builtin_amdgcn_s_barrier();
        // ---- odd phase: tile ti+1 (regs aO, bO from sA[nxt]) ----
        if (ti + 2 < nt) { BLOAD(bE, ti + 2); AREAD(aE0, aE1, wr); }
        if (ti + 4 < nt) LOADA(vaA0, vaA1, (ti + 4) * 32);
        if (ti + 1 < nt) MFMA3(aO0, aO1, bO);
        if (ti + 3 < nt) WRITEA(cur, vaB0, vaB1);
        asm volatile("s_waitcnt lgkmcnt(0)" ::: "memory");
        __builtin_amdgcn_s_barrier();
        cur = wr;
    }

    // epilogue: logit = acc/256; C/D: col=lane&31, row=(r&3)+8*(r>>2)+4*(lane>>5)
    const float s0 = 1.f / 256.f;
#pragma unroll
    for (int h = 0; h < 2; ++h)
#pragma unroll
        for (int n = 0; n < 2; ++n)
#pragma unroll
            for (int r = 0; r < 16; ++r) {
                const int row = (r & 3) + 8 * (r >> 2) + 4 * (lane >> 5);
                const int gr  = m0 + h * 32 + row;
                const int gc  = w * 64 + n * 32 + (lane & 31);
                P[((size_t)ks * TDIM + gr) * EDIM + gc] = acc[h][n][r] * s0;
            }
}

// ---------------- K3: reduce + sigmoid + grouped top-k route ----------------
__global__ __launch_bounds__(256, 4)
void route_kernel(const float* __restrict__ P,
                  const float* __restrict__ B,
                  float* __restrict__ out,
                  int splitK)
{
    const int t    = threadIdx.x;
    const int lane = t & 63;
    const int wid  = t >> 6;
    const int tok0 = blockIdx.x * 32 + wid * 8;

    const float4 bv4 = *(const float4*)&B[lane * 4];
    const float bb[4] = {bv4.x, bv4.y, bv4.z, bv4.w};
    const int g = lane >> 3;

#pragma unroll
    for (int i = 0; i < 8; ++i) {
        const int tok = tok0 + i;
        float a[4] = {0.f, 0.f, 0.f, 0.f};
        for (int ksl = 0; ksl < splitK; ++ksl) {
            const float4 pv =
                *(const float4*)&P[((size_t)ksl * TDIM + tok) * EDIM + lane * 4];
            a[0] += pv.x; a[1] += pv.y; a[2] += pv.z; a[3] += pv.w;
        }
        float v[4], s[4];
#pragma unroll
        for (int jq = 0; jq < 4; ++jq) {
            v[jq] = 1.f / (1.f + expf(-a[jq]));
            s[jq] = v[jq] + bb[jq];
        }
        float t1 = s[0], t2 = -FLT_MAX;
#pragma unroll
        for (int jq = 1; jq < 4; ++jq) {
            if (s[jq] > t1) { t2 = t1; t1 = s[jq]; }
            else if (s[jq] > t2) t2 = s[jq];
        }
#pragma unroll
        for (int d = 1; d < 8; d <<= 1) {
            float o1 = __shfl_xor(t1, d);
            float o2 = __shfl_xor(t2, d);
            float n1 = fmaxf(t1, o1);
            float n2 = fmaxf(fminf(t1, o1), fmaxf(t2, o2));
            t1 = n1; t2 = n2;
        }
        const float gsc = t1 + t2;
        float gs[8];
#pragma unroll
        for (int q = 0; q < 8; ++q) gs[q] = __shfl(gsc, q * 8);
        int gmask = 0;
#pragma unroll
        for (int it = 0; it < 4; ++it) {
            float bvv = -FLT_MAX; int bg = 0;
#pragma unroll
            for (int q = 0; q < 8; ++q) {
                const bool avail = ((gmask >> q) & 1) == 0;
                if (avail && gs[q] > bvv) { bvv = gs[q]; bg = q; }
            }
            gmask |= (1 << bg);
        }
        if (((gmask >> g) & 1) == 0) { s[0] = 0.f; s[1] = 0.f; s[2] = 0.f; s[3] = 0.f; }

        float wk[8]; int ik[8]; float wsum = 0.f;
#pragma unroll
        for (int it = 0; it < 8; ++it) {
            float bvv = s[0]; int bi = lane * 4; float bs = v[0];
#pragma unroll
            for (int jq = 1; jq < 4; ++jq)
                if (s[jq] > bvv) { bvv = s[jq]; bi = lane * 4 + jq; bs = v[jq]; }
#pragma unroll
            for (int d = 1; d < 64; d <<= 1) {
                float ov = __shfl_xor(bvv, d);
                int   oi = __shfl_xor(bi, d);
                float os = __shfl_xor(bs, d);
                if (ov > bvv || (ov == bvv && oi < bi)) { bvv = ov; bi = oi; bs = os; }
            }
            wk[it] = bs; ik[it] = bi; wsum += bs;
#pragma unroll
            for (int jq = 0; jq < 4; ++jq)
                if (bi == lane * 4 + jq) s[jq] = -FLT_MAX;
        }
        const float den = wsum + 1e-20f;
        if (lane == 0) {
#pragma unroll
            for (int q = 0; q < 8; ++q) {
                out[(size_t)tok * 8 + q] = wk[q] / den * 2.5f;
                out[(size_t)TDIM * 8 + (size_t)tok * 8 + q] = (float)ik[q];
            }
        }
    }
}

extern "C" void kernel_launch(void* const* d_in, const int* in_sizes, int n_in,
                              void* d_out, int out_size, void* d_ws, size_t ws_size,
                              hipStream_t stream)
{
    (void)in_sizes; (void)n_in; (void)out_size;
    const float* x    = (const float*)d_in[0];
    const float* kern = (const float*)d_in[1];
    const float* bias = (const float*)d_in[2];
    float* out = (float*)d_out;

    const size_t packedBytes = (size_t)2 * 8 * KT * 2 * 512 * 2;   // 7.34 MB
    int splitK = 4;
    while (splitK > 1 &&
           (size_t)splitK * TDIM * EDIM * 4 + packedBytes > ws_size)
        splitK >>= 1;

    float* P = (float*)d_ws;
    _Float16* Bp = (_Float16*)((char*)d_ws + (size_t)splitK * TDIM * EDIM * 4);

    convert_w<<<dim3(DDIM / 64, EDIM / 64), 256, 0, stream>>>(kern, Bp);
    gemm_mfma<<<(TDIM / 64) * splitK, 256, 0, stream>>>(
        x, Bp, P, splitK, DDIM / splitK);
    route_kernel<<<TDIM / 32, 256, 0, stream>>>(P, bias, out, splitK);
}